// Round 1
// baseline (47.809 us; speedup 1.0000x reference)
//
#include <hip/hip_runtime.h>

#define NCLS 7

// Workspace header layout (at the start of d_ws, viewed as 8 x 4-byte slots):
//   [0] int   anchor
//   [1] int   a_cls
//   [2] float pos_num
//   [3] float neg_num
//   [4] float inv_norm(anc_t)
//   [5] float inv_norm(anc_v)
//   [6] float inv_norm(anc_a)
//   [7] pad
// followed by 2*nblocks float partials (pos,neg per block).

struct Hdr {
    int   anchor;
    int   a_cls;
    float pos_num;
    float neg_num;
    float inv_at;
    float inv_av;
    float inv_aa;
    float pad;
};

__device__ __forceinline__ float dot4(float4 a, float4 b) {
    return a.x * b.x + a.y * b.y + a.z * b.z + a.w * b.w;
}

// ---------------------------------------------------------------------------
// Kernel A: label histogram -> a_cls -> anchor -> anchor-row inverse norms.
// Single block; trivially cheap vs the 96 MiB main pass.
// ---------------------------------------------------------------------------
__global__ __launch_bounds__(256) void prep_kernel(
    const int* __restrict__ label,
    const float* __restrict__ s_t,
    const float* __restrict__ s_v,
    const float* __restrict__ s_a,
    int B, int D, float* __restrict__ ws)
{
    __shared__ int   hist[NCLS];
    __shared__ int   minIdx;
    __shared__ int   s_acls;
    __shared__ float wsum[3][4];

    const int tid = threadIdx.x;
    if (tid < NCLS) hist[tid] = 0;
    if (tid == 0) minIdx = 0x7fffffff;
    __syncthreads();

    for (int i = tid; i < B; i += blockDim.x)
        atomicAdd(&hist[label[i]], 1);
    __syncthreads();

    if (tid == 0) {
        // jnp.argmax(counts > 1): first class with count>1, else 0.
        int c = 0;
        for (int k = 0; k < NCLS; ++k) {
            if (hist[k] > 1) { c = k; break; }
        }
        s_acls = c;
    }
    __syncthreads();

    const int acls = s_acls;
    for (int i = tid; i < B; i += blockDim.x)
        if (label[i] == acls) atomicMin(&minIdx, i);
    __syncthreads();

    const int anchor = minIdx;

    // sum of squares of the three anchor rows
    const float* rt = s_t + (size_t)anchor * D;
    const float* rv = s_v + (size_t)anchor * D;
    const float* ra = s_a + (size_t)anchor * D;
    float st = 0.f, sv = 0.f, sa = 0.f;
    for (int j = tid; j < D; j += blockDim.x) {
        float t = rt[j], v = rv[j], a = ra[j];
        st += t * t; sv += v * v; sa += a * a;
    }
    for (int off = 32; off; off >>= 1) {
        st += __shfl_xor(st, off);
        sv += __shfl_xor(sv, off);
        sa += __shfl_xor(sa, off);
    }
    const int w = tid >> 6, lane = tid & 63;
    if (lane == 0) { wsum[0][w] = st; wsum[1][w] = sv; wsum[2][w] = sa; }
    __syncthreads();

    if (tid == 0) {
        float tt = wsum[0][0] + wsum[0][1] + wsum[0][2] + wsum[0][3];
        float vv = wsum[1][0] + wsum[1][1] + wsum[1][2] + wsum[1][3];
        float aa = wsum[2][0] + wsum[2][1] + wsum[2][2] + wsum[2][3];
        Hdr* h = (Hdr*)ws;
        h->anchor  = anchor;
        h->a_cls   = acls;
        float pn   = (float)hist[acls];
        h->pos_num = pn;
        h->neg_num = (float)B - pn;
        h->inv_at  = rsqrtf(tt);
        h->inv_av  = rsqrtf(vv);
        h->inv_aa  = rsqrtf(aa);
    }
}

// ---------------------------------------------------------------------------
// Kernel B: one wave per row. Stream the row of each modality once (float4),
// accumulate 2 dots (vs the other two modalities' anchor rows) + 1 sumsq per
// modality, shuffle-reduce, classify, emit per-block pos/neg partials.
// Anchor rows (12 KB total) stay hot in L1/L2.
// ---------------------------------------------------------------------------
__global__ __launch_bounds__(256) void main_kernel(
    const int* __restrict__ label,
    const float* __restrict__ s_t,
    const float* __restrict__ s_v,
    const float* __restrict__ s_a,
    int B, int D, float* __restrict__ ws)
{
    const Hdr* h = (const Hdr*)ws;
    float* partials = ws + 8;

    const int   anchor = h->anchor;
    const int   acls   = h->a_cls;
    const float inv_at = h->inv_at;
    const float inv_av = h->inv_av;
    const float inv_aa = h->inv_aa;

    const int w = threadIdx.x >> 6, lane = threadIdx.x & 63;
    const int r = blockIdx.x * 4 + w;

    __shared__ float pos_part[4], neg_part[4];

    float rowtot = 0.f;
    bool isPos = false, isNeg = false;

    if (r < B) {
        const float4* rt = (const float4*)(s_t + (size_t)r * D);
        const float4* rv = (const float4*)(s_v + (size_t)r * D);
        const float4* ra = (const float4*)(s_a + (size_t)r * D);
        const float4* at = (const float4*)(s_t + (size_t)anchor * D);
        const float4* av = (const float4*)(s_v + (size_t)anchor * D);
        const float4* aa = (const float4*)(s_a + (size_t)anchor * D);

        float dt_a = 0.f, dt_v = 0.f, sq_t = 0.f;
        float dv_t = 0.f, dv_a = 0.f, sq_v = 0.f;
        float da_t = 0.f, da_v = 0.f, sq_a = 0.f;

        const int nvec = D >> 2;
        for (int j = lane; j < nvec; j += 64) {
            float4 t  = rt[j], v  = rv[j], a  = ra[j];
            float4 bt = at[j], bv = av[j], ba = aa[j];
            dt_a += dot4(t, ba);
            dt_v += dot4(t, bv);
            sq_t += dot4(t, t);
            dv_t += dot4(v, bt);
            dv_a += dot4(v, ba);
            sq_v += dot4(v, v);
            da_t += dot4(a, bt);
            da_v += dot4(a, bv);
            sq_a += dot4(a, a);
        }
        for (int off = 32; off; off >>= 1) {
            dt_a += __shfl_xor(dt_a, off);
            dt_v += __shfl_xor(dt_v, off);
            sq_t += __shfl_xor(sq_t, off);
            dv_t += __shfl_xor(dv_t, off);
            dv_a += __shfl_xor(dv_a, off);
            sq_v += __shfl_xor(sq_v, off);
            da_t += __shfl_xor(da_t, off);
            da_v += __shfl_xor(da_v, off);
            sq_a += __shfl_xor(sq_a, off);
        }
        if (lane == 0) {
            float inv_t = rsqrtf(sq_t);
            float inv_v = rsqrtf(sq_v);
            float inv_a = rsqrtf(sq_a);
            rowtot = inv_t * (dt_a * inv_aa + dt_v * inv_av)
                   + inv_v * (dv_t * inv_at + dv_a * inv_aa)
                   + inv_a * (da_t * inv_at + da_v * inv_av);
            int lab = label[r];
            isPos = (lab == acls) && (r != anchor);
            isNeg = (lab != acls);
        }
    }

    if (lane == 0) {
        pos_part[w] = isPos ? rowtot : 0.f;
        neg_part[w] = isNeg ? rowtot : 0.f;
    }
    __syncthreads();
    if (threadIdx.x == 0) {
        partials[2 * blockIdx.x]     = pos_part[0] + pos_part[1] + pos_part[2] + pos_part[3];
        partials[2 * blockIdx.x + 1] = neg_part[0] + neg_part[1] + neg_part[2] + neg_part[3];
    }
}

// ---------------------------------------------------------------------------
// Kernel C: deterministic reduction of per-block partials -> scalar loss.
// loss = (6 - pos_total/pos_num + neg_total/neg_num) / 3
// ---------------------------------------------------------------------------
__global__ __launch_bounds__(256) void finish_kernel(
    const float* __restrict__ ws, int nblocks, float* __restrict__ out)
{
    const Hdr* h = (const Hdr*)ws;
    const float* partials = ws + 8;

    float p = 0.f, n = 0.f;
    for (int i = threadIdx.x; i < nblocks; i += blockDim.x) {
        p += partials[2 * i];
        n += partials[2 * i + 1];
    }
    for (int off = 32; off; off >>= 1) {
        p += __shfl_xor(p, off);
        n += __shfl_xor(n, off);
    }
    __shared__ float pp[4], nn[4];
    const int w = threadIdx.x >> 6, lane = threadIdx.x & 63;
    if (lane == 0) { pp[w] = p; nn[w] = n; }
    __syncthreads();
    if (threadIdx.x == 0) {
        float P = pp[0] + pp[1] + pp[2] + pp[3];
        float N = nn[0] + nn[1] + nn[2] + nn[3];
        out[0] = (6.0f - P / h->pos_num + N / h->neg_num) / 3.0f;
    }
}

extern "C" void kernel_launch(void* const* d_in, const int* in_sizes, int n_in,
                              void* d_out, int out_size, void* d_ws, size_t ws_size,
                              hipStream_t stream) {
    const int*   label = (const int*)d_in[0];
    const float* s_t   = (const float*)d_in[1];
    const float* s_v   = (const float*)d_in[2];
    const float* s_a   = (const float*)d_in[3];

    const int B = in_sizes[0];
    const int D = in_sizes[1] / B;   // 1024

    float* ws  = (float*)d_ws;
    float* out = (float*)d_out;

    const int nblocks = (B + 3) / 4; // one wave (of 4 per block) per row

    prep_kernel<<<1, 256, 0, stream>>>(label, s_t, s_v, s_a, B, D, ws);
    main_kernel<<<nblocks, 256, 0, stream>>>(label, s_t, s_v, s_a, B, D, ws);
    finish_kernel<<<1, 256, 0, stream>>>(ws, nblocks, out);
}